// Round 12
// baseline (222.429 us; speedup 1.0000x reference)
//
#include <hip/hip_runtime.h>
#include <hip/hip_bf16.h>

#define B_ 2
#define T_ 2048
#define E_ 1024
#define DK 256
#define DV 512
#define MROWS 4096      // B_*T_
#define LDQKVG 6144     // q(1024) k(1024) v->og(2048) g(2048)
#define CHK 128         // retention chunk size
#define NCHK 16         // T_/CHK

typedef __attribute__((ext_vector_type(8))) short short8;
typedef __attribute__((ext_vector_type(4))) short short4v;
typedef __attribute__((ext_vector_type(4))) float floatx4;

typedef __attribute__((address_space(3))) unsigned as3_u32;
typedef const __attribute__((address_space(1))) unsigned as1_u32;

static __device__ __forceinline__ void gld_lds16(const unsigned short* gsrc, unsigned short* ldst) {
  __builtin_amdgcn_global_load_lds((as1_u32*)gsrc, (as3_u32*)ldst, 16, 0, 0);
}

static __device__ __forceinline__ float bf2f(unsigned short u) {
  union { unsigned int i; float f; } x; x.i = ((unsigned int)u) << 16; return x.f;
}
static __device__ __forceinline__ unsigned short f2bf(float f) {
  __hip_bfloat16 h = __float2bfloat16(f);
  return __builtin_bit_cast(unsigned short, h);
}

// ---------------- prep: convx | Wq..Wg transpose | rope table | Wo transpose ------
__global__ void __launch_bounds__(256) prep_kernel(
    const float* __restrict__ x, unsigned short* __restrict__ xb,
    const float* __restrict__ Wq, const float* __restrict__ Wk,
    const float* __restrict__ Wv, const float* __restrict__ Wg,
    unsigned short* __restrict__ WallT,
    const float* __restrict__ Wo, unsigned short* __restrict__ WoT,
    float2* __restrict__ ropetab) {
  __shared__ float tile[32][33];
  int bid = blockIdx.x;
  int tid = threadIdx.x;
  if (bid < 2048) {                       // convx: x -> bf16
    int i = bid * 256 + tid;
    size_t base = (size_t)i * 8;
    float4 a = *(const float4*)(x + base);
    float4 b = *(const float4*)(x + base + 4);
    short8 o;
    o[0] = (short)f2bf(a.x); o[1] = (short)f2bf(a.y);
    o[2] = (short)f2bf(a.z); o[3] = (short)f2bf(a.w);
    o[4] = (short)f2bf(b.x); o[5] = (short)f2bf(b.y);
    o[6] = (short)f2bf(b.z); o[7] = (short)f2bf(b.w);
    *(short8*)(xb + base) = o;
    return;
  }
  if (bid < 8192) {                       // Wq|Wk|Wv|Wg -> WallT (transposed bf16)
    bid -= 2048;
    const float* in; unsigned short* o; int ldin, nbx;
    if (bid < 1024)      { in = Wq; o = WallT;                       ldin = 1024; nbx = 32; }
    else if (bid < 2048) { in = Wk; o = WallT + (size_t)1024 * 1024; ldin = 1024; nbx = 32; bid -= 1024; }
    else if (bid < 4096) { in = Wv; o = WallT + (size_t)2048 * 1024; ldin = 2048; nbx = 64; bid -= 2048; }
    else                 { in = Wg; o = WallT + (size_t)4096 * 1024; ldin = 2048; nbx = 64; bid -= 4096; }
    int c0 = (bid % nbx) * 32, r0 = (bid / nbx) * 32;
    int tx = tid & 31, ty = tid >> 5;
#pragma unroll
    for (int i = 0; i < 32; i += 8)
      tile[ty + i][tx] = in[(size_t)(r0 + ty + i) * ldin + c0 + tx];
    __syncthreads();
#pragma unroll
    for (int i = 0; i < 32; i += 8)
      o[(size_t)(c0 + ty + i) * 1024 + r0 + tx] = f2bf(tile[tx][ty + i]);
    return;
  }
  if (bid < 9216) {                       // rope cos/sin table
    int idx = (bid - 8192) * 256 + tid;   // 2048*128
    int t = idx >> 7, j = idx & 127;
    float invf = exp2f(-(float)j * (13.287712379549449f / 128.0f));
    float ang = (float)t * invf;
    ropetab[idx] = make_float2(cosf(ang), sinf(ang));
    return;
  }
  {                                       // Wo (2048x1024) -> WoT (1024x2048)
    int lb = bid - 9216;                  // 2048 blocks
    int c0 = (lb & 31) * 32, r0 = (lb >> 5) * 32;
    int tx = tid & 31, ty = tid >> 5;
#pragma unroll
    for (int i = 0; i < 32; i += 8)
      tile[ty + i][tx] = Wo[(size_t)(r0 + ty + i) * 1024 + c0 + tx];
    __syncthreads();
#pragma unroll
    for (int i = 0; i < 32; i += 8)
      WoT[(size_t)(c0 + ty + i) * 2048 + r0 + tx] = f2bf(tile[tx][ty + i]);
  }
}

// ---------------- 8-wave 256x256 BK=64 double-buffered GEMM (proj) ----------------
// C[m][n] = sum_k A[m][k]*Bt[n][k], bf16 out. 512 thr = 8 waves (2M x 4N),
// wave tile 128x64. LDS 128KB: [slot][A|B][256*64] swizzled (c16 ^= row&7).
// Counted vmcnt(8): each wave issues exactly 8 gld_lds per K-tile stage.
template<int NBX>
__global__ void __launch_bounds__(512, 2) gemm8_kernel(
    const unsigned short* __restrict__ A, int lda,
    const unsigned short* __restrict__ Bt, int ldb, int K,
    unsigned short* __restrict__ Cp, int ldc) {
  __shared__ __align__(16) unsigned short lds[2][2][256 * 64];   // 128 KB
  const int tid = threadIdx.x;
  const int lane = tid & 63;
  const int wid = tid >> 6;
  const int wm = wid >> 2, wn = wid & 3;
  const int m0 = (blockIdx.x % NBX) * 256;
  const int n0 = (blockIdx.x / NBX) * 256;
  const unsigned short* Ab = A + (size_t)m0 * lda;
  const unsigned short* Bb = Bt + (size_t)n0 * ldb;
  const int NT = K / 64;

  auto stage = [&](int sl, int t) {
    const int k0 = t * 64;
#pragma unroll
    for (int j = 0; j < 8; ++j) {
      int cb = j * 512 + wid * 64;            // wave-uniform chunk base (0..4095)
      int ci = cb + lane;
      int arr = cb >> 11;                     // 0: A (chunks 0-2047), 1: B
      int ci2 = ci & 2047;
      int row = ci2 >> 3, c16 = ci2 & 7;
      int cs = c16 ^ (row & 7);               // inverse swizzle on SOURCE
      const unsigned short* src = (arr == 0)
          ? Ab + (size_t)row * lda + k0 + cs * 8
          : Bb + (size_t)row * ldb + k0 + cs * 8;
      gld_lds16(src, &lds[sl][arr][(cb & 2047) * 8]);
    }
  };

  floatx4 acc[8][4];
#pragma unroll
  for (int f = 0; f < 8; ++f)
#pragma unroll
    for (int g = 0; g < 4; ++g)
      acc[f][g] = (floatx4){0.f, 0.f, 0.f, 0.f};

  stage(0, 0);
  stage(1, 1);

  int cur = 0;
#pragma unroll 1
  for (int t = 0; t < NT; ++t) {
    if (t + 1 < NT) asm volatile("s_waitcnt vmcnt(8)" ::: "memory");
    else            asm volatile("s_waitcnt vmcnt(0)" ::: "memory");
    __builtin_amdgcn_s_barrier();             // slot cur = tile t, valid for all waves
    asm volatile("" ::: "memory");

    const unsigned short* Al = lds[cur][0];
    const unsigned short* Bl = lds[cur][1];
    auto rdA = [&](int f, int s) -> short8 {
      int row = wm * 128 + f * 16 + (lane & 15);
      int c16 = s * 4 + (lane >> 4);
      return *(const short8*)&Al[row * 64 + ((c16 ^ (row & 7)) * 8)];
    };
    auto rdB = [&](int g, int s) -> short8 {
      int row = wn * 64 + g * 16 + (lane & 15);
      int c16 = s * 4 + (lane >> 4);
      return *(const short8*)&Bl[row * 64 + ((c16 ^ (row & 7)) * 8)];
    };

    short8 bfr[4][2];
#pragma unroll
    for (int g = 0; g < 4; ++g) { bfr[g][0] = rdB(g, 0); bfr[g][1] = rdB(g, 1); }
    short8 afA0 = rdA(0, 0), afA1 = rdA(0, 1);
    short8 afB0, afB1;
#pragma unroll
    for (int f = 0; f < 8; ++f) {
      if (f < 7) {                            // prefetch next m-frag pair
        if (f & 1) { afA0 = rdA(f + 1, 0); afA1 = rdA(f + 1, 1); }
        else       { afB0 = rdA(f + 1, 0); afB1 = rdA(f + 1, 1); }
      }
      const short8 a0 = (f & 1) ? afB0 : afA0;
      const short8 a1 = (f & 1) ? afB1 : afA1;
      __builtin_amdgcn_s_setprio(1);
#pragma unroll
      for (int g = 0; g < 4; ++g) {
        acc[f][g] = __builtin_amdgcn_mfma_f32_16x16x32_bf16(a0, bfr[g][0], acc[f][g], 0, 0, 0);
        acc[f][g] = __builtin_amdgcn_mfma_f32_16x16x32_bf16(a1, bfr[g][1], acc[f][g], 0, 0, 0);
      }
      __builtin_amdgcn_s_setprio(0);
    }
    asm volatile("s_waitcnt lgkmcnt(0)" ::: "memory");
    __builtin_amdgcn_s_barrier();             // all waves done reading slot cur
    asm volatile("" ::: "memory");
    if (t + 2 < NT) stage(cur, t + 2);        // refill freed slot; lands by t+2
    cur ^= 1;
  }

#pragma unroll
  for (int f = 0; f < 8; ++f)
#pragma unroll
    for (int g = 0; g < 4; ++g)
#pragma unroll
      for (int r = 0; r < 4; ++r) {
        int row = m0 + wm * 128 + f * 16 + (lane >> 4) * 4 + r;
        int col = n0 + wn * 64 + g * 16 + (lane & 15);
        Cp[(size_t)row * ldc + col] = f2bf(acc[f][g][r]);
      }
}

// ---------------- pipelined GEMM: ring-3, prefetch 2, counted vmcnt (out-GEMM) -----
template<int BM, int BN, int WM_W, int WN_W, int MINW, bool F32OUT>
__global__ void __launch_bounds__(WM_W * WN_W * 64, MINW) gemmp_kernel(
    const unsigned short* __restrict__ A, int lda,
    const unsigned short* __restrict__ Bt, int ldb, int K,
    void* __restrict__ Cp, int ldc, int ccol0, int nbx) {
  constexpr int WAVES = WM_W * WN_W;
  constexpr int AG = BM / 16 / WAVES;
  constexpr int BG = BN / 16 / WAVES;
  constexpr int RM = BM / WM_W;
  constexpr int CN = BN / WN_W;
  constexpr int MB = RM / 16, NB = CN / 16;
  __shared__ __align__(16) unsigned short lds[3][(BM + BN) * 32];
  const int tid = threadIdx.x;
  const int lane = tid & 63;
  const int wid = tid >> 6;
  const int wm = wid / WN_W, wn = wid % WN_W;
  const int bid = blockIdx.x;
  const int m0 = (bid % nbx) * BM;
  const int n0 = (bid / nbx) * BN;
  const unsigned short* Ab = A + (size_t)m0 * lda;
  const unsigned short* Bb = Bt + (size_t)n0 * ldb;
  const int NT = K / 32;

  auto stage = [&](int sl, int t) {
    const int k0 = t * 32;
#pragma unroll
    for (int j = 0; j < AG; ++j) {
      int g = wid * AG + j;
      int ci = g * 64 + lane;
      int row = ci >> 2, c = ci & 3;
      int cs = c ^ ((row >> 1) & 3);
      gld_lds16(Ab + (size_t)row * lda + k0 + cs * 8, &lds[sl][g * 512]);
    }
#pragma unroll
    for (int j = 0; j < BG; ++j) {
      int g = wid * BG + j;
      int ci = g * 64 + lane;
      int row = ci >> 2, c = ci & 3;
      int cs = c ^ ((row >> 1) & 3);
      gld_lds16(Bb + (size_t)row * ldb + k0 + cs * 8, &lds[sl][BM * 32 + g * 512]);
    }
  };

  floatx4 acc[MB][NB];
#pragma unroll
  for (int i = 0; i < MB; i++)
#pragma unroll
    for (int j = 0; j < NB; j++)
      acc[i][j] = (floatx4){0.f, 0.f, 0.f, 0.f};

  stage(0, 0);
  stage(1, 1);

  int cur = 0;
#pragma unroll 1
  for (int t = 0; t < NT; ++t) {
    if (t + 1 < NT) {
      if constexpr (AG + BG == 2) asm volatile("s_waitcnt vmcnt(2)" ::: "memory");
      else if constexpr (AG + BG == 3) asm volatile("s_waitcnt vmcnt(3)" ::: "memory");
      else if constexpr (AG + BG == 4) asm volatile("s_waitcnt vmcnt(4)" ::: "memory");
      else if constexpr (AG + BG == 6) asm volatile("s_waitcnt vmcnt(6)" ::: "memory");
      else asm volatile("s_waitcnt vmcnt(8)" ::: "memory");
    } else {
      asm volatile("s_waitcnt vmcnt(0)" ::: "memory");
    }
    __builtin_amdgcn_s_barrier();
    asm volatile("" ::: "memory");
    int sl = cur + 2; if (sl >= 3) sl -= 3;
    if (t + 2 < NT) stage(sl, t + 2);

    const unsigned short* As_ = lds[cur];
    const unsigned short* Bs_ = lds[cur] + BM * 32;
    short8 af[MB], bfv[NB];
#pragma unroll
    for (int i = 0; i < MB; ++i) {
      int row = wm * RM + i * 16 + (lane & 15);
      af[i] = *(const short8*)&As_[row * 32 + (((lane >> 4) ^ ((row >> 1) & 3)) * 8)];
    }
#pragma unroll
    for (int j = 0; j < NB; ++j) {
      int nn = wn * CN + j * 16 + (lane & 15);
      bfv[j] = *(const short8*)&Bs_[nn * 32 + (((lane >> 4) ^ ((nn >> 1) & 3)) * 8)];
    }
#pragma unroll
    for (int i = 0; i < MB; ++i)
#pragma unroll
      for (int j = 0; j < NB; ++j)
        acc[i][j] = __builtin_amdgcn_mfma_f32_16x16x32_bf16(af[i], bfv[j], acc[i][j], 0, 0, 0);
    cur = cur + 1 == 3 ? 0 : cur + 1;
  }

#pragma unroll
  for (int i = 0; i < MB; ++i)
#pragma unroll
    for (int j = 0; j < NB; ++j)
#pragma unroll
      for (int r = 0; r < 4; ++r) {
        int row = m0 + wm * RM + i * 16 + (lane >> 4) * 4 + r;
        int col = ccol0 + n0 + wn * CN + j * 16 + (lane & 15);
        float v = acc[i][j][r];
        if (F32OUT) ((float*)Cp)[(size_t)row * ldc + col] = v;
        else ((unsigned short*)Cp)[(size_t)row * ldc + col] = f2bf(v);
      }
}

// ---------------- postproc: RoPE(q,k) in place + scaled kT + vT, one pass ---------
__global__ void __launch_bounds__(256) postproc_kernel(
    unsigned short* __restrict__ qkvg, const float2* __restrict__ tab,
    unsigned short* __restrict__ kTs, unsigned short* __restrict__ vT) {
  __shared__ unsigned short kt[256][33];
  __shared__ unsigned short vt[512][33];
  const int tid = threadIdx.x;
  const int rt = blockIdx.x >> 2, h = blockIdx.x & 3;
  const int grow0 = rt * 32;
  const float lg = log2f(1.0f - exp2f(-5.0f - (float)h));
  const int r = tid >> 3;                 // 0..31
  const int grow = grow0 + r;
  const int t = grow & (T_ - 1);
  const float sq = 0.0625f * exp2f((float)(t & (CHK - 1)) * lg);
  const float fac = exp2f((float)(CHK - (t & (CHK - 1))) * lg);
#pragma unroll
  for (int half = 0; half < 2; ++half) {
    int j0 = (tid & 7) * 8 + half * 64;
    size_t base = (size_t)grow * LDQKVG + h * DK + j0;
    short8 q1 = *(const short8*)&qkvg[base],      q2 = *(const short8*)&qkvg[base + 128];
    short8 k1 = *(const short8*)&qkvg[base + E_], k2 = *(const short8*)&qkvg[base + E_ + 128];
    short8 oq1, oq2, ok1, ok2;
#pragma unroll
    for (int e = 0; e < 8; ++e) {
      float2 cs = tab[(t << 7) + j0 + e];
      float c = cs.x, s = cs.y;
      float a1 = bf2f((unsigned short)q1[e]), a2 = bf2f((unsigned short)q2[e]);
      float b1 = bf2f((unsigned short)k1[e]), b2 = bf2f((unsigned short)k2[e]);
      float rk1 = b1 * c - b2 * s, rk2 = b2 * c + b1 * s;
      oq1[e] = (short)f2bf((a1 * c - a2 * s) * sq);
      oq2[e] = (short)f2bf((a2 * c + a1 * s) * sq);
      ok1[e] = (short)f2bf(rk1);
      ok2[e] = (short)f2bf(rk2);
      kt[j0 + e][r]       = f2bf(rk1 * fac);
      kt[j0 + e + 128][r] = f2bf(rk2 * fac);
    }
    *(short8*)&qkvg[base]            = oq1;
    *(short8*)&qkvg[base + 128]      = oq2;
    *(short8*)&qkvg[base + E_]       = ok1;
    *(short8*)&qkvg[base + E_ + 128] = ok2;
  }
  __syncthreads();
  {
    int dk = tid;
    unsigned short* dst = kTs + (size_t)(h * DK + dk) * MROWS + grow0;
#pragma unroll
    for (int i = 0; i < 4; ++i) {
      short8 w;
#pragma unroll
      for (int e = 0; e < 8; ++e) w[e] = (short)kt[dk][i * 8 + e];
      *(short8*)(dst + i * 8) = w;
    }
  }
  {
    int cv = tid & 7;
#pragma unroll
    for (int i = 0; i < 8; ++i) {
      int col = cv * 64 + i * 8;
      short8 v = *(const short8*)&qkvg[(size_t)grow * LDQKVG + 2048 + h * DV + col];
#pragma unroll
      for (int e = 0; e < 8; ++e) vt[col + e][r] = (unsigned short)v[e];
    }
  }
  __syncthreads();
#pragma unroll
  for (int p = 0; p < 2; ++p) {
    int dv = p * 256 + tid;
    unsigned short* dst = vT + (size_t)(h * DV + dv) * MROWS + grow0;
#pragma unroll
    for (int i = 0; i < 4; ++i) {
      short8 w;
#pragma unroll
      for (int e = 0; e < 8; ++e) w[e] = (short)vt[dv][i * 8 + e];
      *(short8*)(dst + i * 8) = w;
    }
  }
}

// ---------------- state scan: S_{c+1} = gamma^CHK * S_c + K'^T V ----------------
__global__ void __launch_bounds__(256) state_kernel(
    const unsigned short* __restrict__ kTs, const unsigned short* __restrict__ vT,
    unsigned short* __restrict__ Sbuf) {
  const int lane = threadIdx.x & 63, wid = threadIdx.x >> 6;
  const int bh = blockIdx.x & 7, dkt = (blockIdx.x >> 3) & 3, dvt = (blockIdx.x >> 5) & 15;
  const int b = bh >> 2, h = bh & 3;
  const float lg = log2f(1.0f - exp2f(-5.0f - (float)h));
  const float g128 = exp2f((float)CHK * lg);
  const int dk0 = dkt * 64 + wid * 16;
  const int dv0 = dvt * 32;
  const unsigned short* arow = kTs + (size_t)(h * DK + dk0 + (lane & 15)) * MROWS + b * T_ + (lane >> 4) * 8;
  const unsigned short* brow = vT + (size_t)(h * DV + dv0 + (lane & 15)) * MROWS + b * T_ + (lane >> 4) * 8;
  floatx4 acc[2];
  acc[0] = (floatx4){0.f, 0.f, 0.f, 0.f};
  acc[1] = (floatx4){0.f, 0.f, 0.f, 0.f};
#pragma unroll 4
  for (int c = 0; c < NCHK; ++c) {
    size_t sb = (size_t)(c * 8 + bh) * (DV * DK);
#pragma unroll
    for (int nb = 0; nb < 2; ++nb) {
      short4v o;
#pragma unroll
      for (int r = 0; r < 4; ++r) o[r] = (short)f2bf(acc[nb][r]);
      *(short4v*)&Sbuf[sb + (size_t)(dv0 + nb * 16 + (lane & 15)) * DK + dk0 + (lane >> 4) * 4] = o;
    }
#pragma unroll
    for (int nb = 0; nb < 2; ++nb)
#pragma unroll
      for (int r = 0; r < 4; ++r) acc[nb][r] *= g128;
#pragma unroll
    for (int ks = 0; ks < 4; ++ks) {
      short8 a = *(const short8*)(arow + c * CHK + ks * 32);
#pragma unroll
      for (int nb = 0; nb < 2; ++nb) {
        short8 bb = *(const short8*)(brow + (size_t)nb * 16 * MROWS + c * CHK + ks * 32);
        acc[nb] = __builtin_amdgcn_mfma_f32_16x16x32_bf16(a, bb, acc[nb], 0, 0, 0);
      }
    }
  }
}

// ---------------- retention3: intra + cross-chunk + FULL RMS + gate ----------------
__global__ void __launch_bounds__(256) retention3_kernel(
    const unsigned short* __restrict__ qkvg, const unsigned short* __restrict__ vT,
    const unsigned short* __restrict__ Sbuf, const float* __restrict__ gnw,
    unsigned short* __restrict__ og) {
  __shared__ unsigned short k_lds[32 * 256];
  __shared__ unsigned short v_lds[512 * 32];
  __shared__ unsigned short s_lds[4][16 * 40];
  const int tid = threadIdx.x, lane = tid & 63, wid = tid >> 6;
  const int bh  = blockIdx.x & 7;
  const int c   = (blockIdx.x >> 3) & 15;
  const int rhf = (blockIdx.x >> 7) & 1;
  const int b = bh >> 2, h = bh & 3;
  const float lg = log2f(1.0f - exp2f(-5.0f - (float)h));
  const int rb0 = b * T_ + c * CHK + rhf * 64;
  const int taub = rhf * 64 + wid * 16;
  const int nst = rhf ? 4 : 2;
  const unsigned short* kbase = qkvg + (size_t)(b * T_ + c * CHK) * LDQKVG + E_ + h * DK;
  const unsigned short* vbase = vT + (size_t)(h * DV) * MROWS + b * T_ + c * CHK;
  const unsigned short* Sp = Sbuf + (size_t)(c * 8 + bh) * (DV * DK);

  auto stage = [&](int st) {
    int s0 = st * 32;
#pragma unroll
    for (int j = 0; j < 4; ++j) {
      int ci = (wid * 4 + j) * 64 + lane;
      int row = ci >> 5, cc = ci & 31;
      int cs = cc ^ (row & 7);
      gld_lds16(kbase + (size_t)(s0 + row) * LDQKVG + cs * 8, &k_lds[(wid * 4 + j) * 512]);
    }
#pragma unroll
    for (int j = 0; j < 8; ++j) {
      int ci = (wid * 8 + j) * 64 + lane;
      int dv = ci >> 2, cc = ci & 3;
      int cs = cc ^ ((dv ^ (dv >> 2)) & 3);
      gld_lds16(vbase + (size_t)dv * MROWS + s0 + cs * 8, &v_lds[(wid * 8 + j) * 512]);
    }
  };

  stage(0);

  short8 qf[8];
  {
    int qrow = rb0 + wid * 16 + (lane & 15);
    const unsigned short* qp = qkvg + (size_t)qrow * LDQKVG + h * DK + (lane >> 4) * 8;
#pragma unroll
    for (int kk = 0; kk < 8; kk++) qf[kk] = *(const short8*)(qp + kk * 32);
  }
  floatx4 oacc[32];
#pragma unroll
  for (int nb = 0; nb < 32; ++nb) oacc[nb] = (floatx4){0.f, 0.f, 0.f, 0.f};
#pragma unroll
  for (int ks = 0; ks < 8; ++ks) {
#pragma unroll
    for (int nb = 0; nb < 32; ++nb) {
      short8 sf = *(const short8*)&Sp[(size_t)(nb * 16 + (lane & 15)) * DK + ks * 32 + (lane >> 4) * 8];
      oacc[nb] = __builtin_amdgcn_mfma_f32_16x16x32_bf16(qf[ks], sf, oacc[nb], 0, 0, 0);
    }
  }

#pragma unroll 1
  for (int st = 0; st < nst; ++st) {
    __syncthreads();
#pragma unroll
    for (int ch = 0; ch < 2; ++ch) {
      floatx4 f = (floatx4){0.f, 0.f, 0.f, 0.f};
      const int srow = ch * 16 + (lane & 15);
      __builtin_amdgcn_s_setprio(1);
#pragma unroll
      for (int kk = 0; kk < 8; kk++) {
        int cc = (kk * 4 + (lane >> 4)) ^ (srow & 7);
        short8 kf = *(const short8*)&k_lds[srow * 256 + cc * 8];
        f = __builtin_amdgcn_mfma_f32_16x16x32_bf16(qf[kk], kf, f, 0, 0, 0);
      }
      __builtin_amdgcn_s_setprio(0);
#pragma unroll
      for (int r = 0; r < 4; ++r) {
        int lr = (lane >> 4) * 4 + r;
        int sig = st * 32 + ch * 16 + (lane & 15);
        int n = taub + lr - sig;
        float val = (n >= 0) ? f[r] * exp2f(-(float)sig * lg) : 0.0f;
        s_lds[wid][lr * 40 + ch * 16 + (lane & 15)] = f2bf(val);
      }
    }
    short8 af = *(const short8*)&s_lds[wid][(lane & 15) * 40 + (lane >> 4) * 8];
    __builtin_amdgcn_s_setprio(1);
#pragma unroll
    for (int nb = 0; nb < 32; ++nb) {
      int dv = nb * 16 + (lane & 15);
      int cc = (lane >> 4) ^ ((dv ^ (dv >> 2)) & 3);
      short8 vf = *(const short8*)&v_lds[dv * 32 + cc * 8];
      oacc[nb] = __builtin_amdgcn_mfma_f32_16x16x32_bf16(af, vf, oacc[nb], 0, 0, 0);
    }
    __builtin_amdgcn_s_setprio(0);
    if (st + 1 < nst) {
      __syncthreads();
      stage(st + 1);
    }
  }
#pragma unroll
  for (int r = 0; r < 4; ++r) {
    float ss = 0.f;
#pragma unroll
    for (int nb = 0; nb < 32; nb++) { float xv = oacc[nb][r]; ss += xv * xv; }
    ss += __shfl_xor(ss, 1, 64);
    ss += __shfl_xor(ss, 2, 64);
    ss += __shfl_xor(ss, 4, 64);
    ss += __shfl_xor(ss, 8, 64);
    float inv = rsqrtf(ss * (1.0f / 512.0f) + 1e-5f);
    int row = rb0 + wid * 16 + (lane >> 4) * 4 + r;
    size_t growbase = (size_t)row * LDQKVG + 4096 + h * DV;
    size_t orowbase = (size_t)row * LDQKVG + h * DV;
#pragma unroll
    for (int nb = 0; nb < 32; nb++) {
      int col = nb * 16 + (lane & 15);
      float gv = bf2f(qkvg[growbase + col]);
      og[orowbase + col] = f2bf(oacc[nb][r] * inv * gnw[col] * gv);
    }
  }
}

extern "C" void kernel_launch(void* const* d_in, const int* in_sizes, int n_in,
                              void* d_out, int out_size, void* d_ws, size_t ws_size,
                              hipStream_t stream) {
  const float* x   = (const float*)d_in[0];
  const float* Wq  = (const float*)d_in[1];
  const float* Wk  = (const float*)d_in[2];
  const float* Wv  = (const float*)d_in[3];
  const float* Wg  = (const float*)d_in[4];
  const float* Wo  = (const float*)d_in[5];
  const float* gnw = (const float*)d_in[6];
  float* out = (float*)d_out;

  char* ws = (char*)d_ws;
  size_t off = 0;
  auto alloc = [&](size_t bytes) { char* p = ws + off; off += (bytes + 255) & ~(size_t)255; return p; };
  unsigned short* qkvg = (unsigned short*)alloc((size_t)MROWS * LDQKVG * 2);
  unsigned short* vT   = (unsigned short*)alloc((size_t)2048 * MROWS * 2);
  char* regS = alloc((size_t)NCHK * 8 * DV * DK * 2);
  unsigned short* Sbuf  = (unsigned short*)regS;            // after projection
  unsigned short* xb    = (unsigned short*)regS;            // pre-projection
  unsigned short* WallT = (unsigned short*)(regS + 8388608);
  unsigned short* kTs = (unsigned short*)alloc((size_t)1024 * MROWS * 2);
  unsigned short* WoT = (unsigned short*)alloc((size_t)1024 * 2048 * 2);
  float2* ropetab = (float2*)alloc((size_t)T_ * 128 * 8);
  unsigned short* og = qkvg + 2048;

  prep_kernel<<<11264, 256, 0, stream>>>(x, xb, Wq, Wk, Wv, Wg, WallT, Wo, WoT, ropetab);

  // fused q|k|v|g projection: 4096 x 6144 x 1024; 256x256 BK=64, 8-wave, dbuf+counted vmcnt
  gemm8_kernel<16><<<384, 512, 0, stream>>>(xb, 1024, WallT, 1024, 1024, qkvg, LDQKVG);

  postproc_kernel<<<512, 256, 0, stream>>>(qkvg, ropetab, kTs, vT);

  state_kernel<<<512, 256, 0, stream>>>(kTs, vT, Sbuf);

  retention3_kernel<<<256, 256, 0, stream>>>(qkvg, vT, Sbuf, gnw, og);

  gemmp_kernel<128, 128, 2, 2, 3, true><<<256, 256, 0, stream>>>(
      og, LDQKVG, WoT, 2048, 2048, out, E_, 0, 32);
}

// Round 14
// 211.321 us; speedup vs baseline: 1.0526x; 1.0526x over previous
//
#include <hip/hip_runtime.h>
#include <hip/hip_bf16.h>

#define B_ 2
#define T_ 2048
#define E_ 1024
#define DK 256
#define DV 512
#define MROWS 4096      // B_*T_
#define LDQKVG 6144     // q(1024) k(1024) v->og(2048) g(2048)
#define CHK 128         // retention chunk size
#define NCHK 16         // T_/CHK

typedef __attribute__((ext_vector_type(8))) short short8;
typedef __attribute__((ext_vector_type(4))) short short4v;
typedef __attribute__((ext_vector_type(4))) float floatx4;

typedef __attribute__((address_space(3))) unsigned as3_u32;
typedef const __attribute__((address_space(1))) unsigned as1_u32;

static __device__ __forceinline__ void gld_lds16(const unsigned short* gsrc, unsigned short* ldst) {
  __builtin_amdgcn_global_load_lds((as1_u32*)gsrc, (as3_u32*)ldst, 16, 0, 0);
}

static __device__ __forceinline__ float bf2f(unsigned short u) {
  union { unsigned int i; float f; } x; x.i = ((unsigned int)u) << 16; return x.f;
}
static __device__ __forceinline__ unsigned short f2bf(float f) {
  __hip_bfloat16 h = __float2bfloat16(f);
  return __builtin_bit_cast(unsigned short, h);
}

// ---------------- prep: convx | Wq..Wg transpose | rope table | Wo transpose ------
__global__ void __launch_bounds__(256) prep_kernel(
    const float* __restrict__ x, unsigned short* __restrict__ xb,
    const float* __restrict__ Wq, const float* __restrict__ Wk,
    const float* __restrict__ Wv, const float* __restrict__ Wg,
    unsigned short* __restrict__ WallT,
    const float* __restrict__ Wo, unsigned short* __restrict__ WoT,
    float2* __restrict__ ropetab) {
  __shared__ float tile[32][33];
  int bid = blockIdx.x;
  int tid = threadIdx.x;
  if (bid < 2048) {                       // convx: x -> bf16
    int i = bid * 256 + tid;
    size_t base = (size_t)i * 8;
    float4 a = *(const float4*)(x + base);
    float4 b = *(const float4*)(x + base + 4);
    short8 o;
    o[0] = (short)f2bf(a.x); o[1] = (short)f2bf(a.y);
    o[2] = (short)f2bf(a.z); o[3] = (short)f2bf(a.w);
    o[4] = (short)f2bf(b.x); o[5] = (short)f2bf(b.y);
    o[6] = (short)f2bf(b.z); o[7] = (short)f2bf(b.w);
    *(short8*)(xb + base) = o;
    return;
  }
  if (bid < 8192) {                       // Wq|Wk|Wv|Wg -> WallT (transposed bf16)
    bid -= 2048;
    const float* in; unsigned short* o; int ldin, nbx;
    if (bid < 1024)      { in = Wq; o = WallT;                       ldin = 1024; nbx = 32; }
    else if (bid < 2048) { in = Wk; o = WallT + (size_t)1024 * 1024; ldin = 1024; nbx = 32; bid -= 1024; }
    else if (bid < 4096) { in = Wv; o = WallT + (size_t)2048 * 1024; ldin = 2048; nbx = 64; bid -= 2048; }
    else                 { in = Wg; o = WallT + (size_t)4096 * 1024; ldin = 2048; nbx = 64; bid -= 4096; }
    int c0 = (bid % nbx) * 32, r0 = (bid / nbx) * 32;
    int tx = tid & 31, ty = tid >> 5;
#pragma unroll
    for (int i = 0; i < 32; i += 8)
      tile[ty + i][tx] = in[(size_t)(r0 + ty + i) * ldin + c0 + tx];
    __syncthreads();
#pragma unroll
    for (int i = 0; i < 32; i += 8)
      o[(size_t)(c0 + ty + i) * 1024 + r0 + tx] = f2bf(tile[tx][ty + i]);
    return;
  }
  if (bid < 9216) {                       // rope cos/sin table
    int idx = (bid - 8192) * 256 + tid;   // 2048*128
    int t = idx >> 7, j = idx & 127;
    float invf = exp2f(-(float)j * (13.287712379549449f / 128.0f));
    float ang = (float)t * invf;
    ropetab[idx] = make_float2(cosf(ang), sinf(ang));
    return;
  }
  {                                       // Wo (2048x1024) -> WoT (1024x2048)
    int lb = bid - 9216;                  // 2048 blocks
    int c0 = (lb & 31) * 32, r0 = (lb >> 5) * 32;
    int tx = tid & 31, ty = tid >> 5;
#pragma unroll
    for (int i = 0; i < 32; i += 8)
      tile[ty + i][tx] = Wo[(size_t)(r0 + ty + i) * 1024 + c0 + tx];
    __syncthreads();
#pragma unroll
    for (int i = 0; i < 32; i += 8)
      WoT[(size_t)(c0 + ty + i) * 2048 + r0 + tx] = f2bf(tile[tx][ty + i]);
  }
}

// ---------------- pipelined GEMM: ring-3, prefetch 2, counted vmcnt ----------------
// C[m][ccol0+n] = sum_k A[m][k]*Bt[n][k]. WAVES = WM_W*WN_W (block = WAVES*64 thr).
// Wave tile = (BM/WM_W) x (BN/WN_W). 1-D grid, m-tile fastest (round-robin XCD).
template<int BM, int BN, int WM_W, int WN_W, int MINW, bool F32OUT>
__global__ void __launch_bounds__(WM_W * WN_W * 64, MINW) gemmp_kernel(
    const unsigned short* __restrict__ A, int lda,
    const unsigned short* __restrict__ Bt, int ldb, int K,
    void* __restrict__ Cp, int ldc, int ccol0, int nbx) {
  constexpr int WAVES = WM_W * WN_W;
  constexpr int AG = BM / 16 / WAVES;
  constexpr int BG = BN / 16 / WAVES;
  constexpr int RM = BM / WM_W;
  constexpr int CN = BN / WN_W;
  constexpr int MB = RM / 16, NB = CN / 16;
  __shared__ __align__(16) unsigned short lds[3][(BM + BN) * 32];
  const int tid = threadIdx.x;
  const int lane = tid & 63;
  const int wid = tid >> 6;
  const int wm = wid / WN_W, wn = wid % WN_W;
  const int bid = blockIdx.x;
  const int m0 = (bid % nbx) * BM;
  const int n0 = (bid / nbx) * BN;
  const unsigned short* Ab = A + (size_t)m0 * lda;
  const unsigned short* Bb = Bt + (size_t)n0 * ldb;
  const int NT = K / 32;

  auto stage = [&](int sl, int t) {
    const int k0 = t * 32;
#pragma unroll
    for (int j = 0; j < AG; ++j) {
      int g = wid * AG + j;
      int ci = g * 64 + lane;
      int row = ci >> 2, c = ci & 3;
      int cs = c ^ ((row >> 1) & 3);      // inverse swizzle on SOURCE
      gld_lds16(Ab + (size_t)row * lda + k0 + cs * 8, &lds[sl][g * 512]);
    }
#pragma unroll
    for (int j = 0; j < BG; ++j) {
      int g = wid * BG + j;
      int ci = g * 64 + lane;
      int row = ci >> 2, c = ci & 3;
      int cs = c ^ ((row >> 1) & 3);
      gld_lds16(Bb + (size_t)row * ldb + k0 + cs * 8, &lds[sl][BM * 32 + g * 512]);
    }
  };

  floatx4 acc[MB][NB];
#pragma unroll
  for (int i = 0; i < MB; i++)
#pragma unroll
    for (int j = 0; j < NB; j++)
      acc[i][j] = (floatx4){0.f, 0.f, 0.f, 0.f};

  stage(0, 0);
  stage(1, 1);

  int cur = 0;
#pragma unroll 1
  for (int t = 0; t < NT; ++t) {
    if (t + 1 < NT) {
      if constexpr (AG + BG == 2) asm volatile("s_waitcnt vmcnt(2)" ::: "memory");
      else if constexpr (AG + BG == 3) asm volatile("s_waitcnt vmcnt(3)" ::: "memory");
      else if constexpr (AG + BG == 4) asm volatile("s_waitcnt vmcnt(4)" ::: "memory");
      else if constexpr (AG + BG == 6) asm volatile("s_waitcnt vmcnt(6)" ::: "memory");
      else asm volatile("s_waitcnt vmcnt(8)" ::: "memory");
    } else {
      asm volatile("s_waitcnt vmcnt(0)" ::: "memory");
    }
    __builtin_amdgcn_s_barrier();
    asm volatile("" ::: "memory");
    int sl = cur + 2; if (sl >= 3) sl -= 3;
    if (t + 2 < NT) stage(sl, t + 2);

    const unsigned short* As_ = lds[cur];
    const unsigned short* Bs_ = lds[cur] + BM * 32;
    short8 af[MB], bfv[NB];
#pragma unroll
    for (int i = 0; i < MB; ++i) {
      int row = wm * RM + i * 16 + (lane & 15);
      af[i] = *(const short8*)&As_[row * 32 + (((lane >> 4) ^ ((row >> 1) & 3)) * 8)];
    }
#pragma unroll
    for (int j = 0; j < NB; ++j) {
      int nn = wn * CN + j * 16 + (lane & 15);
      bfv[j] = *(const short8*)&Bs_[nn * 32 + (((lane >> 4) ^ ((nn >> 1) & 3)) * 8)];
    }
#pragma unroll
    for (int i = 0; i < MB; ++i)
#pragma unroll
      for (int j = 0; j < NB; ++j)
        acc[i][j] = __builtin_amdgcn_mfma_f32_16x16x32_bf16(af[i], bfv[j], acc[i][j], 0, 0, 0);
    cur = cur + 1 == 3 ? 0 : cur + 1;
  }

#pragma unroll
  for (int i = 0; i < MB; ++i)
#pragma unroll
    for (int j = 0; j < NB; ++j)
#pragma unroll
      for (int r = 0; r < 4; ++r) {
        int row = m0 + wm * RM + i * 16 + (lane >> 4) * 4 + r;
        int col = ccol0 + n0 + wn * CN + j * 16 + (lane & 15);
        float v = acc[i][j][r];
        if (F32OUT) ((float*)Cp)[(size_t)row * ldc + col] = v;
        else ((unsigned short*)Cp)[(size_t)row * ldc + col] = f2bf(v);
      }
}

// ---------------- postproc: RoPE(q,k) in place + scaled kT + vT, one pass ---------
__global__ void __launch_bounds__(256) postproc_kernel(
    unsigned short* __restrict__ qkvg, const float2* __restrict__ tab,
    unsigned short* __restrict__ kTs, unsigned short* __restrict__ vT) {
  __shared__ unsigned short kt[256][33];
  __shared__ unsigned short vt[512][33];
  const int tid = threadIdx.x;
  const int rt = blockIdx.x >> 2, h = blockIdx.x & 3;
  const int grow0 = rt * 32;
  const float lg = log2f(1.0f - exp2f(-5.0f - (float)h));
  const int r = tid >> 3;                 // 0..31
  const int grow = grow0 + r;
  const int t = grow & (T_ - 1);
  const float sq = 0.0625f * exp2f((float)(t & (CHK - 1)) * lg);
  const float fac = exp2f((float)(CHK - (t & (CHK - 1))) * lg);
#pragma unroll
  for (int half = 0; half < 2; ++half) {
    int j0 = (tid & 7) * 8 + half * 64;
    size_t base = (size_t)grow * LDQKVG + h * DK + j0;
    short8 q1 = *(const short8*)&qkvg[base],      q2 = *(const short8*)&qkvg[base + 128];
    short8 k1 = *(const short8*)&qkvg[base + E_], k2 = *(const short8*)&qkvg[base + E_ + 128];
    short8 oq1, oq2, ok1, ok2;
#pragma unroll
    for (int e = 0; e < 8; ++e) {
      float2 cs = tab[(t << 7) + j0 + e];
      float c = cs.x, s = cs.y;
      float a1 = bf2f((unsigned short)q1[e]), a2 = bf2f((unsigned short)q2[e]);
      float b1 = bf2f((unsigned short)k1[e]), b2 = bf2f((unsigned short)k2[e]);
      float rk1 = b1 * c - b2 * s, rk2 = b2 * c + b1 * s;
      oq1[e] = (short)f2bf((a1 * c - a2 * s) * sq);
      oq2[e] = (short)f2bf((a2 * c + a1 * s) * sq);
      ok1[e] = (short)f2bf(rk1);
      ok2[e] = (short)f2bf(rk2);
      kt[j0 + e][r]       = f2bf(rk1 * fac);
      kt[j0 + e + 128][r] = f2bf(rk2 * fac);
    }
    *(short8*)&qkvg[base]            = oq1;
    *(short8*)&qkvg[base + 128]      = oq2;
    *(short8*)&qkvg[base + E_]       = ok1;
    *(short8*)&qkvg[base + E_ + 128] = ok2;
  }
  __syncthreads();
  {
    int dk = tid;
    unsigned short* dst = kTs + (size_t)(h * DK + dk) * MROWS + grow0;
#pragma unroll
    for (int i = 0; i < 4; ++i) {
      short8 w;
#pragma unroll
      for (int e = 0; e < 8; ++e) w[e] = (short)kt[dk][i * 8 + e];
      *(short8*)(dst + i * 8) = w;
    }
  }
  {
    int cv = tid & 7;
#pragma unroll
    for (int i = 0; i < 8; ++i) {
      int col = cv * 64 + i * 8;
      short8 v = *(const short8*)&qkvg[(size_t)grow * LDQKVG + 2048 + h * DV + col];
#pragma unroll
      for (int e = 0; e < 8; ++e) vt[col + e][r] = (unsigned short)v[e];
    }
  }
  __syncthreads();
#pragma unroll
  for (int p = 0; p < 2; ++p) {
    int dv = p * 256 + tid;
    unsigned short* dst = vT + (size_t)(h * DV + dv) * MROWS + grow0;
#pragma unroll
    for (int i = 0; i < 4; ++i) {
      short8 w;
#pragma unroll
      for (int e = 0; e < 8; ++e) w[e] = (short)vt[dv][i * 8 + e];
      *(short8*)(dst + i * 8) = w;
    }
  }
}

// ---------------- state scan: S_{c+1} = gamma^CHK * S_c + K'^T V ----------------
__global__ void __launch_bounds__(256) state_kernel(
    const unsigned short* __restrict__ kTs, const unsigned short* __restrict__ vT,
    unsigned short* __restrict__ Sbuf) {
  const int lane = threadIdx.x & 63, wid = threadIdx.x >> 6;
  const int bh = blockIdx.x & 7, dkt = (blockIdx.x >> 3) & 3, dvt = (blockIdx.x >> 5) & 15;
  const int b = bh >> 2, h = bh & 3;
  const float lg = log2f(1.0f - exp2f(-5.0f - (float)h));
  const float g128 = exp2f((float)CHK * lg);
  const int dk0 = dkt * 64 + wid * 16;
  const int dv0 = dvt * 32;
  const unsigned short* arow = kTs + (size_t)(h * DK + dk0 + (lane & 15)) * MROWS + b * T_ + (lane >> 4) * 8;
  const unsigned short* brow = vT + (size_t)(h * DV + dv0 + (lane & 15)) * MROWS + b * T_ + (lane >> 4) * 8;
  floatx4 acc[2];
  acc[0] = (floatx4){0.f, 0.f, 0.f, 0.f};
  acc[1] = (floatx4){0.f, 0.f, 0.f, 0.f};
#pragma unroll 4
  for (int c = 0; c < NCHK; ++c) {
    size_t sb = (size_t)(c * 8 + bh) * (DV * DK);
#pragma unroll
    for (int nb = 0; nb < 2; ++nb) {
      short4v o;
#pragma unroll
      for (int r = 0; r < 4; ++r) o[r] = (short)f2bf(acc[nb][r]);
      *(short4v*)&Sbuf[sb + (size_t)(dv0 + nb * 16 + (lane & 15)) * DK + dk0 + (lane >> 4) * 4] = o;
    }
#pragma unroll
    for (int nb = 0; nb < 2; ++nb)
#pragma unroll
      for (int r = 0; r < 4; ++r) acc[nb][r] *= g128;
#pragma unroll
    for (int ks = 0; ks < 4; ++ks) {
      short8 a = *(const short8*)(arow + c * CHK + ks * 32);
#pragma unroll
      for (int nb = 0; nb < 2; ++nb) {
        short8 bb = *(const short8*)(brow + (size_t)nb * 16 * MROWS + c * CHK + ks * 32);
        acc[nb] = __builtin_amdgcn_mfma_f32_16x16x32_bf16(a, bb, acc[nb], 0, 0, 0);
      }
    }
  }
}

// ---------------- retention3: intra + cross-chunk + FULL RMS + gate ----------------
__global__ void __launch_bounds__(256) retention3_kernel(
    const unsigned short* __restrict__ qkvg, const unsigned short* __restrict__ vT,
    const unsigned short* __restrict__ Sbuf, const float* __restrict__ gnw,
    unsigned short* __restrict__ og) {
  __shared__ unsigned short k_lds[32 * 256];
  __shared__ unsigned short v_lds[512 * 32];
  __shared__ unsigned short s_lds[4][16 * 40];
  const int tid = threadIdx.x, lane = tid & 63, wid = tid >> 6;
  const int bh  = blockIdx.x & 7;
  const int c   = (blockIdx.x >> 3) & 15;
  const int rhf = (blockIdx.x >> 7) & 1;
  const int b = bh >> 2, h = bh & 3;
  const float lg = log2f(1.0f - exp2f(-5.0f - (float)h));
  const int rb0 = b * T_ + c * CHK + rhf * 64;
  const int taub = rhf * 64 + wid * 16;
  const int nst = rhf ? 4 : 2;
  const unsigned short* kbase = qkvg + (size_t)(b * T_ + c * CHK) * LDQKVG + E_ + h * DK;
  const unsigned short* vbase = vT + (size_t)(h * DV) * MROWS + b * T_ + c * CHK;
  const unsigned short* Sp = Sbuf + (size_t)(c * 8 + bh) * (DV * DK);

  auto stage = [&](int st) {
    int s0 = st * 32;
#pragma unroll
    for (int j = 0; j < 4; ++j) {
      int ci = (wid * 4 + j) * 64 + lane;
      int row = ci >> 5, cc = ci & 31;
      int cs = cc ^ (row & 7);
      gld_lds16(kbase + (size_t)(s0 + row) * LDQKVG + cs * 8, &k_lds[(wid * 4 + j) * 512]);
    }
#pragma unroll
    for (int j = 0; j < 8; ++j) {
      int ci = (wid * 8 + j) * 64 + lane;
      int dv = ci >> 2, cc = ci & 3;
      int cs = cc ^ ((dv ^ (dv >> 2)) & 3);
      gld_lds16(vbase + (size_t)dv * MROWS + s0 + cs * 8, &v_lds[(wid * 8 + j) * 512]);
    }
  };

  stage(0);

  short8 qf[8];
  {
    int qrow = rb0 + wid * 16 + (lane & 15);
    const unsigned short* qp = qkvg + (size_t)qrow * LDQKVG + h * DK + (lane >> 4) * 8;
#pragma unroll
    for (int kk = 0; kk < 8; kk++) qf[kk] = *(const short8*)(qp + kk * 32);
  }
  floatx4 oacc[32];
#pragma unroll
  for (int nb = 0; nb < 32; ++nb) oacc[nb] = (floatx4){0.f, 0.f, 0.f, 0.f};
#pragma unroll
  for (int ks = 0; ks < 8; ++ks) {
#pragma unroll
    for (int nb = 0; nb < 32; ++nb) {
      short8 sf = *(const short8*)&Sp[(size_t)(nb * 16 + (lane & 15)) * DK + ks * 32 + (lane >> 4) * 8];
      oacc[nb] = __builtin_amdgcn_mfma_f32_16x16x32_bf16(qf[ks], sf, oacc[nb], 0, 0, 0);
    }
  }

#pragma unroll 1
  for (int st = 0; st < nst; ++st) {
    __syncthreads();
#pragma unroll
    for (int ch = 0; ch < 2; ++ch) {
      floatx4 f = (floatx4){0.f, 0.f, 0.f, 0.f};
      const int srow = ch * 16 + (lane & 15);
      __builtin_amdgcn_s_setprio(1);
#pragma unroll
      for (int kk = 0; kk < 8; kk++) {
        int cc = (kk * 4 + (lane >> 4)) ^ (srow & 7);
        short8 kf = *(const short8*)&k_lds[srow * 256 + cc * 8];
        f = __builtin_amdgcn_mfma_f32_16x16x32_bf16(qf[kk], kf, f, 0, 0, 0);
      }
      __builtin_amdgcn_s_setprio(0);
#pragma unroll
      for (int r = 0; r < 4; ++r) {
        int lr = (lane >> 4) * 4 + r;
        int sig = st * 32 + ch * 16 + (lane & 15);
        int n = taub + lr - sig;
        float val = (n >= 0) ? f[r] * exp2f(-(float)sig * lg) : 0.0f;
        s_lds[wid][lr * 40 + ch * 16 + (lane & 15)] = f2bf(val);
      }
    }
    short8 af = *(const short8*)&s_lds[wid][(lane & 15) * 40 + (lane >> 4) * 8];
    __builtin_amdgcn_s_setprio(1);
#pragma unroll
    for (int nb = 0; nb < 32; ++nb) {
      int dv = nb * 16 + (lane & 15);
      int cc = (lane >> 4) ^ ((dv ^ (dv >> 2)) & 3);
      short8 vf = *(const short8*)&v_lds[dv * 32 + cc * 8];
      oacc[nb] = __builtin_amdgcn_mfma_f32_16x16x32_bf16(af, vf, oacc[nb], 0, 0, 0);
    }
    __builtin_amdgcn_s_setprio(0);
    if (st + 1 < nst) {
      __syncthreads();
      stage(st + 1);
    }
  }
#pragma unroll
  for (int r = 0; r < 4; ++r) {
    float ss = 0.f;
#pragma unroll
    for (int nb = 0; nb < 32; nb++) { float xv = oacc[nb][r]; ss += xv * xv; }
    ss += __shfl_xor(ss, 1, 64);
    ss += __shfl_xor(ss, 2, 64);
    ss += __shfl_xor(ss, 4, 64);
    ss += __shfl_xor(ss, 8, 64);
    float inv = rsqrtf(ss * (1.0f / 512.0f) + 1e-5f);
    int row = rb0 + wid * 16 + (lane >> 4) * 4 + r;
    size_t growbase = (size_t)row * LDQKVG + 4096 + h * DV;
    size_t orowbase = (size_t)row * LDQKVG + h * DV;
#pragma unroll
    for (int nb = 0; nb < 32; nb++) {
      int col = nb * 16 + (lane & 15);
      float gv = bf2f(qkvg[growbase + col]);
      og[orowbase + col] = f2bf(oacc[nb][r] * inv * gnw[col] * gv);
    }
  }
}

extern "C" void kernel_launch(void* const* d_in, const int* in_sizes, int n_in,
                              void* d_out, int out_size, void* d_ws, size_t ws_size,
                              hipStream_t stream) {
  const float* x   = (const float*)d_in[0];
  const float* Wq  = (const float*)d_in[1];
  const float* Wk  = (const float*)d_in[2];
  const float* Wv  = (const float*)d_in[3];
  const float* Wg  = (const float*)d_in[4];
  const float* Wo  = (const float*)d_in[5];
  const float* gnw = (const float*)d_in[6];
  float* out = (float*)d_out;

  char* ws = (char*)d_ws;
  size_t off = 0;
  auto alloc = [&](size_t bytes) { char* p = ws + off; off += (bytes + 255) & ~(size_t)255; return p; };
  unsigned short* qkvg = (unsigned short*)alloc((size_t)MROWS * LDQKVG * 2);
  unsigned short* vT   = (unsigned short*)alloc((size_t)2048 * MROWS * 2);
  char* regS = alloc((size_t)NCHK * 8 * DV * DK * 2);
  unsigned short* Sbuf  = (unsigned short*)regS;            // after projection
  unsigned short* xb    = (unsigned short*)regS;            // pre-projection
  unsigned short* WallT = (unsigned short*)(regS + 8388608);
  unsigned short* kTs = (unsigned short*)alloc((size_t)1024 * MROWS * 2);
  unsigned short* WoT = (unsigned short*)alloc((size_t)1024 * 2048 * 2);
  float2* ropetab = (float2*)alloc((size_t)T_ * 128 * 8);
  unsigned short* og = qkvg + 2048;

  prep_kernel<<<11264, 256, 0, stream>>>(x, xb, Wq, Wk, Wv, Wg, WallT, Wo, WoT, ropetab);

  // fused q|k|v|g projection: 4096 x 6144 x 1024; 8-wave 64x64, ring-3 (proven config)
  gemmp_kernel<128, 256, 2, 4, 4, false><<<768, 512, 0, stream>>>(
      xb, 1024, WallT, 1024, 1024, qkvg, LDQKVG, 0, 32);

  postproc_kernel<<<512, 256, 0, stream>>>(qkvg, ropetab, kTs, vT);

  state_kernel<<<512, 256, 0, stream>>>(kTs, vT, Sbuf);

  retention3_kernel<<<256, 256, 0, stream>>>(qkvg, vT, Sbuf, gnw, og);

  gemmp_kernel<128, 128, 2, 2, 3, true><<<256, 256, 0, stream>>>(
      og, LDQKVG, WoT, 2048, 2048, out, E_, 0, 32);
}